// Round 2
// baseline (5402.884 us; speedup 1.0000x reference)
//
#include <hip/hip_runtime.h>
#include <math.h>

// Problem constants (from reference): L=512 (batch/spatial), T=96, C=H=150, K=5
#define LB   512
#define TSTEPS 96
#define CIN  150
#define HDIM 150
#define KW   5
#define CO3  450   // 3*H

// fast device math: v_exp_f32-based sigmoid / tanh (rel err ~2^-21)
__device__ __forceinline__ float fsigmoid(float x) {
    return __builtin_amdgcn_rcpf(1.f + __expf(-x));
}
__device__ __forceinline__ float ftanh(float x) {
    // tanh(x) = 2*sigmoid(2x) - 1
    return fmaf(2.f, __builtin_amdgcn_rcpf(1.f + __expf(-2.f * x)), -1.f);
}

// ---------------------------------------------------------------------------
// xi conv: xi[t][b][co] = bias[co] + sum_{k,ci} X[b+k-2][t][ci] * Wi[k][ci][co]
// X element (b',t,ci) at src[b'*srcB + t*srcT + ci]; zero-pad b' outside [0,512).
// xi layout: (T, B, 450) -> xi[(t*512+b)*450 + co]
// grid (32, 96), block 256. Thread tid<225 owns co pair (2tid,2tid+1) x 16 b rows.
// Per ci iter: 10 weight floats (coalesced float2) vs 160 FMAs -> VALU-bound.
// ---------------------------------------------------------------------------
__global__ __launch_bounds__(256) void xi_conv_kernel(
    const float* __restrict__ src, long srcB, long srcT,
    const float* __restrict__ Wi, const float* __restrict__ bias,
    float* __restrict__ xi)
{
    __shared__ float xsh[CIN][20];   // [ci][row], rows = b0-2 .. b0+17 (80B row stride, 16B aligned)
    const int b0  = blockIdx.x * 16;
    const int t   = blockIdx.y;
    const int tid = threadIdx.x;

    for (int idx = tid; idx < 20 * CIN; idx += 256) {
        int row = idx / CIN;
        int ci  = idx - row * CIN;
        int bp  = b0 + row - 2;
        float v = 0.f;
        if (bp >= 0 && bp < LB) v = src[(long)bp * srcB + (long)t * srcT + ci];
        xsh[ci][row] = v;
    }
    __syncthreads();

    if (tid < 225) {
        const int co = 2 * tid;
        float acc0[16], acc1[16];
        #pragma unroll
        for (int b = 0; b < 16; ++b) { acc0[b] = 0.f; acc1[b] = 0.f; }

        for (int ci = 0; ci < CIN; ++ci) {
            // 20 staged x values for this ci — wave-uniform LDS broadcasts
            float4 a0 = *(const float4*)&xsh[ci][0];
            float4 a1 = *(const float4*)&xsh[ci][4];
            float4 a2 = *(const float4*)&xsh[ci][8];
            float4 a3 = *(const float4*)&xsh[ci][12];
            float4 a4 = *(const float4*)&xsh[ci][16];
            float xr[20];
            xr[0]=a0.x; xr[1]=a0.y; xr[2]=a0.z; xr[3]=a0.w;
            xr[4]=a1.x; xr[5]=a1.y; xr[6]=a1.z; xr[7]=a1.w;
            xr[8]=a2.x; xr[9]=a2.y; xr[10]=a2.z; xr[11]=a2.w;
            xr[12]=a3.x; xr[13]=a3.y; xr[14]=a3.z; xr[15]=a3.w;
            xr[16]=a4.x; xr[17]=a4.y; xr[18]=a4.z; xr[19]=a4.w;

            #pragma unroll
            for (int k = 0; k < KW; ++k) {
                const float2 w = *(const float2*)&Wi[((long)(k * CIN + ci)) * CO3 + co];
                #pragma unroll
                for (int b = 0; b < 16; ++b) {
                    float x = xr[b + k];            // compile-time index (k,b unrolled)
                    acc0[b] = fmaf(w.x, x, acc0[b]);
                    acc1[b] = fmaf(w.y, x, acc1[b]);
                }
            }
        }

        const float2 bia = *(const float2*)&bias[co];
        float* xo = xi + ((long)t * LB + b0) * CO3 + co;
        #pragma unroll
        for (int b = 0; b < 16; ++b) {
            float2 o; o.x = acc0[b] + bia.x; o.y = acc1[b] + bia.y;
            *(float2*)&xo[(long)b * CO3] = o;
        }
    }
}

// ---------------------------------------------------------------------------
// One GRU timestep:
//   hh[b][co] = sum_{k,ci} h[b+k-2][ci] * Wh[k][ci][co]          (co = 0..449)
//   r=sig(xr+hr) z=sig(xz+hz) n=tanh(xn+r*hn) h_new=(1-z)n+z*h
// h_prev element (b,j) at hbase[b*hStride + j] (ignored if hvalid==0 -> zeros)
// output element (b,j) at obase[b*oStride + j]
// grid (64, 3), block 384: waves 0-2 = b_sub 0 (rows b0..b0+3), waves 3-5 =
// b_sub 1 (rows b0+4..b0+7); co_local = tid%192 -> gate=co_local>>6, j=j0+(co_local&63).
// ---------------------------------------------------------------------------
__global__ __launch_bounds__(384) void gru_step_kernel(
    const float* __restrict__ hbase, long hStride, int hvalid,
    const float* __restrict__ Wh,
    const float* __restrict__ xit,
    float* __restrict__ obase, long oStride)
{
    __shared__ float hsh[CIN][12];   // [ci][row], rows = b0-2 .. b0+9 (48B stride)
    __shared__ float hhsh[8][192];   // [b_local][co_local]

    const int b0  = blockIdx.x * 8;
    const int j0  = blockIdx.y * 64;
    const int tid = threadIdx.x;
    const int co_local = tid % 192;
    const int b_sub    = tid / 192;          // 0 or 1 (wave-uniform)

    // stage h rows (transposed); zeros for pad rows or t==0
    for (int idx = tid; idx < 12 * CIN; idx += 384) {
        int row = idx / CIN;
        int ci  = idx - row * CIN;
        int bp  = b0 + row - 2;
        float v = 0.f;
        if (hvalid && bp >= 0 && bp < LB) v = hbase[(long)bp * hStride + ci];
        hsh[ci][row] = v;
    }
    __syncthreads();

    const int gate  = co_local >> 6;
    const int j_l   = co_local & 63;
    const int j     = j0 + j_l;
    const int j_eff = (j < HDIM) ? j : (HDIM - 1);   // clamp to stay in-bounds
    const int co    = gate * HDIM + j_eff;

    float acc[4] = {0.f, 0.f, 0.f, 0.f};
    if (hvalid) {
        const int rbase = b_sub * 4;
        #pragma unroll 2                      // 2x independent load batches in flight
        for (int ci = 0; ci < CIN; ++ci) {
            float4 xa = *(const float4*)&hsh[ci][rbase];       // wave-uniform broadcast
            float4 xb = *(const float4*)&hsh[ci][rbase + 4];
            float xr[8];
            xr[0]=xa.x; xr[1]=xa.y; xr[2]=xa.z; xr[3]=xa.w;
            xr[4]=xb.x; xr[5]=xb.y; xr[6]=xb.z; xr[7]=xb.w;
            const float* wp = &Wh[(long)ci * CO3 + co];
            #pragma unroll
            for (int k = 0; k < KW; ++k) {
                float w = wp[(long)k * CIN * CO3];              // coalesced across lanes
                #pragma unroll
                for (int i = 0; i < 4; ++i)
                    acc[i] = fmaf(w, xr[i + k], acc[i]);
            }
        }
    }
    #pragma unroll
    for (int i = 0; i < 4; ++i) hhsh[b_sub * 4 + i][co_local] = acc[i];
    __syncthreads();

    // gate phase: 8 b x 64 j outputs per block
    for (int idx = tid; idx < 8 * 64; idx += 384) {
        int b  = idx >> 6;
        int jl = idx & 63;
        int jj = j0 + jl;
        if (jj < HDIM) {
            int bg = b0 + b;
            const float* xp = &xit[(long)bg * CO3 + jj];
            float xr_ = xp[0];
            float xz_ = xp[HDIM];
            float xn_ = xp[2 * HDIM];
            float hr_ = hhsh[b][jl];
            float hz_ = hhsh[b][64 + jl];
            float hn_ = hhsh[b][128 + jl];
            float hp  = hsh[jj][b + 2];       // stride-12 across lanes: 2-way bank alias = free
            float r = fsigmoid(xr_ + hr_);
            float z = fsigmoid(xz_ + hz_);
            float n = ftanh(fmaf(r, hn_, xn_));
            obase[(long)bg * oStride + jj] = fmaf(z, hp - n, n);  // (1-z)n + z*hp
        }
    }
}

// ---------------------------------------------------------------------------
extern "C" void kernel_launch(void* const* d_in, const int* in_sizes, int n_in,
                              void* d_out, int out_size, void* d_ws, size_t ws_size,
                              hipStream_t stream) {
    const float* xs  = (const float*)d_in[0];
    const float* Wi0 = (const float*)d_in[1];
    const float* bi0 = (const float*)d_in[2];
    const float* Wh0 = (const float*)d_in[3];
    const float* Wi1 = (const float*)d_in[4];
    const float* bi1 = (const float*)d_in[5];
    const float* Wh1 = (const float*)d_in[6];
    float* out = (float*)d_out;

    // workspace: xi (96*512*450 = 22,118,400 f, 88.5 MB) + ys0 (96*512*150 f, 29.5 MB)
    float* xi  = (float*)d_ws;
    float* ys0 = xi + (size_t)TSTEPS * LB * CO3;

    dim3 gxi(32, TSTEPS);
    dim3 gst(64, 3);

    // ---- layer 0 ----
    // xs layout (B,T,C): (b',t,ci) -> b'*14400 + t*150 + ci
    hipLaunchKernelGGL(xi_conv_kernel, gxi, dim3(256), 0, stream,
                       xs, (long)(TSTEPS * CIN), (long)CIN, Wi0, bi0, xi);
    // ys0 layout (T,B,H): slice t is contiguous (B,H) with bStride=H
    for (int t = 0; t < TSTEPS; ++t) {
        const float* hb = (t == 0) ? ys0 : ys0 + (size_t)(t - 1) * LB * HDIM;
        hipLaunchKernelGGL(gru_step_kernel, gst, dim3(384), 0, stream,
                           hb, (long)HDIM, (t ? 1 : 0), Wh0,
                           xi + (size_t)t * LB * CO3,
                           ys0 + (size_t)t * LB * HDIM, (long)HDIM);
    }

    // ---- layer 1 ----
    // src = ys0: (b',t,ci) -> ys0[(t*512+b')*150+ci] -> srcB=150, srcT=76800
    hipLaunchKernelGGL(xi_conv_kernel, gxi, dim3(256), 0, stream,
                       ys0, (long)HDIM, (long)(LB * HDIM), Wi1, bi1, xi);
    // output layout (B,T,H): slice t -> base = out + t*150, bStride = T*H = 14400
    for (int t = 0; t < TSTEPS; ++t) {
        const float* hb = (t == 0) ? out : out + (size_t)(t - 1) * HDIM;
        hipLaunchKernelGGL(gru_step_kernel, gst, dim3(384), 0, stream,
                           hb, (long)(TSTEPS * HDIM), (t ? 1 : 0), Wh1,
                           xi + (size_t)t * LB * CO3,
                           out + (size_t)t * HDIM, (long)(TSTEPS * HDIM));
    }
}